// Round 16
// baseline (1049.362 us; speedup 1.0000x reference)
//
#include <hip/hip_runtime.h>

#define N_WORDS 262144
#define N_TAGS  512
#define BDIM    768
#define MDIM    128
#define KS      32              // K per slice
#define NSL     (BDIM / KS)     // 24 slices
#define BW      64              // words per panel
#define NPAN    4               // panels per block

typedef __attribute__((ext_vector_type(8))) short  bf16x8;
typedef __attribute__((ext_vector_type(4))) float  f32x4;
typedef __attribute__((ext_vector_type(2))) float  f32x2;

// async global->LDS, 16B per lane; dest base must be wave-uniform
#define GLOAD16(ldsdst, gsrc) __builtin_amdgcn_global_load_lds( \
    (const __attribute__((address_space(1))) unsigned int*)(gsrc), \
    (__attribute__((address_space(3))) unsigned int*)(ldsdst), 16, 0, 0)

// RNE fp32 -> bf16 (inputs finite)
__device__ inline unsigned bf16_1(float a) {
    union { float f; unsigned u; } ua; ua.f = a;
    unsigned x = ua.u;
    x += 0x7fffu + ((x >> 16) & 1u);
    return x >> 16;
}
__device__ inline unsigned bf16_2(float a, float b) {
    union { float f; unsigned u; } ua, ub; ua.f = a; ub.f = b;
    unsigned x = ua.u, y = ub.u;
    x += 0x7fffu + ((x >> 16) & 1u);
    y += 0x7fffu + ((y >> 16) & 1u);
    return (x >> 16) | (y & 0xffff0000u);
}
__device__ inline f32x2 ntld2(const float* p) {
    return __builtin_nontemporal_load(reinterpret_cast<const f32x2*>(p));
}

// ---------------------------------------------------------------------------
__global__ __launch_bounds__(128) void tags_kernel(
    const float* __restrict__ tags_embed, const float* __restrict__ tags_W,
    const float* __restrict__ tags_b, const float* __restrict__ words_b,
    unsigned short* __restrict__ Tbf, float* __restrict__ cvec)
{
    __shared__ __align__(16) float sE[BDIM];
    __shared__ float red[128];
    const int t = blockIdx.x;
    const int m = threadIdx.x;

    for (int i = m; i < BDIM; i += 128) sE[i] = tags_embed[(size_t)t * BDIM + i];
    __syncthreads();

    float acc = tags_b[m];
    const float* Wr = tags_W + (size_t)m * BDIM;
    #pragma unroll 8
    for (int b = 0; b < BDIM; b += 4) {
        float4 w4 = *reinterpret_cast<const float4*>(Wr + b);
        float4 e4 = *reinterpret_cast<const float4*>(&sE[b]);
        acc += w4.x * e4.x + w4.y * e4.y + w4.z * e4.z + w4.w * e4.w;
    }
    Tbf[(size_t)t * MDIM + m] = (unsigned short)bf16_1(2.0f * acc);

    red[m] = acc * (2.0f * words_b[m] - acc);
    __syncthreads();
    for (int s = 64; s > 0; s >>= 1) {
        if (m < s) red[m] += red[m + s];
        __syncthreads();
    }
    if (m == 0) cvec[t] = red[0];
}

__global__ __launch_bounds__(256) void wt_kernel(
    const float* __restrict__ W, unsigned short* __restrict__ Wtbf)
{
    __shared__ float sT[32][33];
    const int bm = blockIdx.x & 3, bk = blockIdx.x >> 2;
    const int m0 = bm * 32, k0 = bk * 32;
    const int r = threadIdx.x >> 3, c = threadIdx.x & 7;

    f32x4 w4 = *reinterpret_cast<const f32x4*>(W + (size_t)(m0 + r) * BDIM + k0 + c * 4);
    sT[r][c * 4 + 0] = w4.x;  sT[r][c * 4 + 1] = w4.y;
    sT[r][c * 4 + 2] = w4.z;  sT[r][c * 4 + 3] = w4.w;
    __syncthreads();

    unsigned lo = bf16_2(sT[c * 4 + 0][r], sT[c * 4 + 1][r]);
    unsigned hi = bf16_2(sT[c * 4 + 2][r], sT[c * 4 + 3][r]);
    unsigned long long p = ((unsigned long long)hi << 32) | lo;
    *reinterpret_cast<unsigned long long*>(Wtbf + (size_t)(k0 + r) * MDIM + m0 + c * 4) = p;
}

// GtSl[s][tag][k%32], slice-major
__global__ __launch_bounds__(64) void gt_kernel(
    const unsigned short* __restrict__ Wtbf, const unsigned short* __restrict__ Tbf,
    unsigned short* __restrict__ GtSl)
{
    const int kt = blockIdx.x % 48, tg = blockIdx.x / 48;
    const int k0 = kt * 16, t0 = tg * 64;
    const int n = threadIdx.x & 15, q = threadIdx.x >> 4;

    bf16x8 a[4];
    #pragma unroll
    for (int ks = 0; ks < 4; ++ks)
        a[ks] = *reinterpret_cast<const bf16x8*>(
            Wtbf + (size_t)(k0 + n) * MDIM + ks * 32 + q * 8);

    const int s2  = kt >> 1;
    const int off = (kt & 1) * 16 + 4 * q;

    #pragma unroll
    for (int tt = 0; tt < 4; ++tt) {
        f32x4 acc = (f32x4){0.f, 0.f, 0.f, 0.f};
        #pragma unroll
        for (int ks = 0; ks < 4; ++ks) {
            bf16x8 b = *reinterpret_cast<const bf16x8*>(
                Tbf + (size_t)(t0 + tt * 16 + n) * MDIM + ks * 32 + q * 8);
            acc = __builtin_amdgcn_mfma_f32_16x16x32_bf16(a[ks], b, acc, 0, 0, 0);
        }
        unsigned lo = bf16_2(acc.x, acc.y);
        unsigned hi = bf16_2(acc.z, acc.w);
        unsigned long long p = ((unsigned long long)hi << 32) | lo;
        *reinterpret_cast<unsigned long long*>(
            GtSl + (size_t)s2 * (N_TAGS * KS) + (size_t)(t0 + tt * 16 + n) * KS + off) = p;
    }
}

// ---------------------------------------------------------------------------
// main: dual-panel store-spread. 1024 blocks x 1024 thr (16 waves).
// Panel = 64 words x 512 tags; wave v = tags v*32..+31 (acc[2][4]=32 AGPR).
// While panel p's K-loop runs, panel p-1's stores dribble out as mt-paired
// 128B-per-row packets at slices 0,3,..,21, issued BEFORE the slice's DMAs
// so vmcnt(1) drains [stores,DMAs] and keeps only the E-load in flight.
// ---------------------------------------------------------------------------
__device__ __forceinline__ const float* pro(
    const float* __restrict__ embed, const unsigned short* __restrict__ GtSl,
    unsigned short* sG, unsigned short* sE,
    int v, int lane, int we, int kp, int w0p, f32x2& eOld)
{
    const float* eSrc = embed + (size_t)(w0p + we) * BDIM + kp * 2;
    #pragma unroll
    for (int r = 0; r < 2; ++r)
        GLOAD16(sG + (r * 16 + v) * 512,
                GtSl + (size_t)((r * 16 + v) * 64 + lane) * 8);
    f32x2 e0 = ntld2(eSrc);
    eOld = ntld2(eSrc + KS);
    *reinterpret_cast<unsigned*>(sE + we * KS + kp * 2) = bf16_2(e0.x, e0.y);
    asm volatile("s_waitcnt vmcnt(1) lgkmcnt(0)\n\ts_barrier" ::: "memory");
    return eSrc;
}

template<bool DOST>
__device__ __forceinline__ void kloop(
    const float* __restrict__ eSrc, const unsigned short* __restrict__ GtSl,
    unsigned short* sG, unsigned short* sE,
    const int v, const int lane, const int n, const int q,
    const int we, const int kp, f32x2& eOld,
    f32x4 (&acc)[2][4],
    const f32x4 (&accP)[2][4], const float (&negP)[4], const int w0stP,
    float* __restrict__ out_logp, float* __restrict__ out_p)
{
    #pragma unroll
    for (int mt = 0; mt < 2; ++mt)
        #pragma unroll
        for (int wt = 0; wt < 4; ++wt)
            acc[mt][wt] = (f32x4){0.f, 0.f, 0.f, 0.f};

    #pragma unroll
    for (int s = 0; s < NSL; ++s) {
        const int cur = s & 1, nxt = cur ^ 1;

        // ---- store packet of previous panel (FIRST, so vmcnt drains it) ----
        if constexpr (DOST) {
            if (s % 3 == 0) {
                const int p  = s / 3;           // 0..7
                const int wt = p >> 1;
                const size_t rb = (size_t)(w0stP + wt * 16 + n) * N_TAGS
                                + v * 32 + 4 * q;
                if ((p & 1) == 0) {
                    #pragma unroll
                    for (int mt = 0; mt < 2; ++mt) {
                        f32x4 d = accP[mt][wt] - negP[wt];
                        *reinterpret_cast<f32x4*>(out_logp + rb + mt * 16) = d;
                    }
                } else {
                    #pragma unroll
                    for (int mt = 0; mt < 2; ++mt) {
                        f32x4 d = accP[mt][wt] - negP[wt];
                        f32x4 e;
                        e.x = __expf(d.x); e.y = __expf(d.y);
                        e.z = __expf(d.z); e.w = __expf(d.w);
                        *reinterpret_cast<f32x4*>(out_p + rb + mt * 16) = e;
                    }
                }
            }
        }

        // ---- next Gt slice DMA ----
        if (s + 1 < NSL) {
            #pragma unroll
            for (int r = 0; r < 2; ++r)
                GLOAD16(sG + nxt * (N_TAGS * KS) + (r * 16 + v) * 512,
                        GtSl + (size_t)(s + 1) * (N_TAGS * KS)
                             + (size_t)((r * 16 + v) * 64 + lane) * 8);
        }
        // ---- E-load for slice s+2 (newest; stays in flight) ----
        f32x2 eN;
        if (s + 2 < NSL) eN = ntld2(eSrc + (s + 2) * KS);

        // ---- ds_write E(s+1) ----
        if (s + 1 < NSL)
            *reinterpret_cast<unsigned*>(
                sE + nxt * (BW * KS) + we * KS + kp * 2) = bf16_2(eOld.x, eOld.y);

        // ---- compute slice s ----
        {
            const unsigned short* sGc = sG + cur * (N_TAGS * KS);
            const unsigned short* sEc = sE + cur * (BW * KS);
            bf16x8 a0 = *reinterpret_cast<const bf16x8*>(
                sGc + (v * 32 + n) * KS + q * 8);
            bf16x8 a1 = *reinterpret_cast<const bf16x8*>(
                sGc + (v * 32 + 16 + n) * KS + q * 8);
            #pragma unroll
            for (int wt = 0; wt < 4; ++wt) {
                bf16x8 b = *reinterpret_cast<const bf16x8*>(
                    sEc + (wt * 16 + n) * KS + q * 8);
                acc[0][wt] = __builtin_amdgcn_mfma_f32_16x16x32_bf16(a0, b, acc[0][wt], 0, 0, 0);
                acc[1][wt] = __builtin_amdgcn_mfma_f32_16x16x32_bf16(a1, b, acc[1][wt], 0, 0, 0);
            }
        }

        // ---- counted-wait barrier ----
        if (s + 2 < NSL) {
            asm volatile("s_waitcnt vmcnt(1) lgkmcnt(0)\n\ts_barrier" ::: "memory");
        } else if (s + 1 < NSL) {
            asm volatile("s_waitcnt vmcnt(0) lgkmcnt(0)\n\ts_barrier" ::: "memory");
        }
        eOld = eN;
    }
}

__device__ __forceinline__ void softmax_panel(
    f32x4 (&acc)[2][4], const float* __restrict__ cvec,
    float* sMx, float* sSm,
    const int v, const int n, const int q, float (&neg)[4])
{
    #pragma unroll
    for (int mt = 0; mt < 2; ++mt) {
        f32x4 c4 = *reinterpret_cast<const f32x4*>(cvec + v * 32 + mt * 16 + 4 * q);
        #pragma unroll
        for (int wt = 0; wt < 4; ++wt) acc[mt][wt] += c4;
    }
    #pragma unroll
    for (int wt = 0; wt < 4; ++wt) {
        float m = -3.0e38f;
        #pragma unroll
        for (int mt = 0; mt < 2; ++mt)
            m = fmaxf(m, fmaxf(fmaxf(acc[mt][wt].x, acc[mt][wt].y),
                               fmaxf(acc[mt][wt].z, acc[mt][wt].w)));
        m = fmaxf(m, __shfl_xor(m, 16, 64));
        m = fmaxf(m, __shfl_xor(m, 32, 64));
        float ss = 0.f;
        #pragma unroll
        for (int mt = 0; mt < 2; ++mt)
            ss += __expf(acc[mt][wt].x - m) + __expf(acc[mt][wt].y - m)
                + __expf(acc[mt][wt].z - m) + __expf(acc[mt][wt].w - m);
        ss += __shfl_xor(ss, 16, 64);
        ss += __shfl_xor(ss, 32, 64);
        if (q == 0) {
            sMx[v * 64 + wt * 16 + n] = m;
            sSm[v * 64 + wt * 16 + n] = ss;
        }
    }
    __syncthreads();
    #pragma unroll
    for (int wt = 0; wt < 4; ++wt) {
        const int wd = wt * 16 + n;
        float M = sMx[wd];
        #pragma unroll
        for (int u = 1; u < 16; ++u) M = fmaxf(M, sMx[u * 64 + wd]);
        float S = 0.f;
        #pragma unroll
        for (int u = 0; u < 16; ++u)
            S += sSm[u * 64 + wd] * __expf(sMx[u * 64 + wd] - M);
        neg[wt] = M + __logf(S);
    }
    __syncthreads();
}

__global__ __launch_bounds__(1024, 4) void main_kernel(
    const float* __restrict__ embed,                 // [N][768] fp32
    const unsigned short* __restrict__ GtSl,         // [24][512][32] bf16
    const float* __restrict__ cvec,                  // [512] fp32
    float* __restrict__ out_logp, float* __restrict__ out_p)
{
    __shared__ __align__(16) unsigned short sG[2 * N_TAGS * KS];  // 64 KB
    __shared__ __align__(16) unsigned short sE[2 * BW * KS];      // 8 KB
    __shared__ float sMx[16 * 64];
    __shared__ float sSm[16 * 64];

    const int tid  = threadIdx.x;
    const int lane = tid & 63;
    const int v    = tid >> 6;       // wave 0..15 -> tags v*32..+31
    const int n    = lane & 15;
    const int q    = lane >> 4;
    const int we   = tid >> 4;       // staging word 0..63
    const int kp   = tid & 15;       // staging 2-float granule
    const int w0base = blockIdx.x * (BW * NPAN);

    f32x4 accA[2][4], accB[2][4];
    float negA[4] = {0.f, 0.f, 0.f, 0.f};
    float negB[4] = {0.f, 0.f, 0.f, 0.f};
    f32x2 eOld;
    const float* eSrc;

    // panel 0
    eSrc = pro(embed, GtSl, sG, sE, v, lane, we, kp, w0base, eOld);
    kloop<false>(eSrc, GtSl, sG, sE, v, lane, n, q, we, kp, eOld,
                 accA, accB, negB, 0, out_logp, out_p);
    softmax_panel(accA, cvec, sMx, sSm, v, n, q, negA);

    // panel 1 (stores panel 0)
    eSrc = pro(embed, GtSl, sG, sE, v, lane, we, kp, w0base + BW, eOld);
    kloop<true>(eSrc, GtSl, sG, sE, v, lane, n, q, we, kp, eOld,
                accB, accA, negA, w0base, out_logp, out_p);
    softmax_panel(accB, cvec, sMx, sSm, v, n, q, negB);

    // panel 2 (stores panel 1)
    eSrc = pro(embed, GtSl, sG, sE, v, lane, we, kp, w0base + 2 * BW, eOld);
    kloop<true>(eSrc, GtSl, sG, sE, v, lane, n, q, we, kp, eOld,
                accA, accB, negB, w0base + BW, out_logp, out_p);
    softmax_panel(accA, cvec, sMx, sSm, v, n, q, negA);

    // panel 3 (stores panel 2)
    eSrc = pro(embed, GtSl, sG, sE, v, lane, we, kp, w0base + 3 * BW, eOld);
    kloop<true>(eSrc, GtSl, sG, sE, v, lane, n, q, we, kp, eOld,
                accB, accA, negA, w0base + 2 * BW, out_logp, out_p);
    softmax_panel(accB, cvec, sMx, sSm, v, n, q, negB);

    // final burst: panel 3
    #pragma unroll
    for (int wt = 0; wt < 4; ++wt) {
        const size_t rb = (size_t)(w0base + 3 * BW + wt * 16 + n) * N_TAGS
                        + v * 32 + 4 * q;
        #pragma unroll
        for (int mt = 0; mt < 2; ++mt) {
            f32x4 d = accB[mt][wt] - negB[wt];
            *reinterpret_cast<f32x4*>(out_logp + rb + mt * 16) = d;
            f32x4 e;
            e.x = __expf(d.x); e.y = __expf(d.y);
            e.z = __expf(d.z); e.w = __expf(d.w);
            *reinterpret_cast<f32x4*>(out_p + rb + mt * 16) = e;
        }
    }
}

extern "C" void kernel_launch(void* const* d_in, const int* in_sizes, int n_in,
                              void* d_out, int out_size, void* d_ws, size_t ws_size,
                              hipStream_t stream) {
    const float* tags_embed  = (const float*)d_in[0];
    const float* words_embed = (const float*)d_in[1];
    const float* tags_W      = (const float*)d_in[2];
    const float* tags_b      = (const float*)d_in[3];
    const float* words_W     = (const float*)d_in[4];
    const float* words_b     = (const float*)d_in[5];

    float* out_logp = (float*)d_out;
    float* out_p    = out_logp + (size_t)N_WORDS * N_TAGS;

    // ws: Tbf [512][128] bf16 | cvec [512] f32 | Wtbf [768][128] bf16 |
    //     GtSl [24][512][32] bf16
    unsigned short* Tbf  = (unsigned short*)d_ws;
    float*          cvec = (float*)(Tbf + (size_t)N_TAGS * MDIM);
    unsigned short* Wtbf = (unsigned short*)(cvec + N_TAGS);
    unsigned short* GtSl = Wtbf + (size_t)BDIM * MDIM;

    tags_kernel<<<N_TAGS, 128, 0, stream>>>(tags_embed, tags_W, tags_b, words_b, Tbf, cvec);
    wt_kernel<<<96, 256, 0, stream>>>(words_W, Wtbf);
    gt_kernel<<<384, 64, 0, stream>>>(Wtbf, Tbf, GtSl);
    main_kernel<<<N_WORDS / (BW * NPAN), 1024, 0, stream>>>(
        words_embed, GtSl, cvec, out_logp, out_p);
}

// Round 17
// 677.452 us; speedup vs baseline: 1.5490x; 1.5490x over previous
//
#include <hip/hip_runtime.h>

#define N_WORDS 262144
#define N_TAGS  512
#define BDIM    768
#define MDIM    128
#define KS      32              // K per slice
#define NSL     (BDIM / KS)     // 24 slices
#define BW      64              // words per block
#define SLB     (N_TAGS * KS)   // ushorts per sG slice buffer (32 KB)

typedef __attribute__((ext_vector_type(8))) short  bf16x8;
typedef __attribute__((ext_vector_type(4))) float  f32x4;
typedef __attribute__((ext_vector_type(2))) float  f32x2;

// async global->LDS, 16B per lane; dest base must be wave-uniform
#define GLOAD16(ldsdst, gsrc) __builtin_amdgcn_global_load_lds( \
    (const __attribute__((address_space(1))) unsigned int*)(gsrc), \
    (__attribute__((address_space(3))) unsigned int*)(ldsdst), 16, 0, 0)

// RNE fp32 -> bf16 (inputs finite)
__device__ inline unsigned bf16_1(float a) {
    union { float f; unsigned u; } ua; ua.f = a;
    unsigned x = ua.u;
    x += 0x7fffu + ((x >> 16) & 1u);
    return x >> 16;
}
__device__ inline unsigned bf16_2(float a, float b) {
    union { float f; unsigned u; } ua, ub; ua.f = a; ub.f = b;
    unsigned x = ua.u, y = ub.u;
    x += 0x7fffu + ((x >> 16) & 1u);
    y += 0x7fffu + ((y >> 16) & 1u);
    return (x >> 16) | (y & 0xffff0000u);
}
__device__ inline f32x2 ntld2(const float* p) {
    return __builtin_nontemporal_load(reinterpret_cast<const f32x2*>(p));
}

// ---------------------------------------------------------------------------
__global__ __launch_bounds__(128) void tags_kernel(
    const float* __restrict__ tags_embed, const float* __restrict__ tags_W,
    const float* __restrict__ tags_b, const float* __restrict__ words_b,
    unsigned short* __restrict__ Tbf, float* __restrict__ cvec)
{
    __shared__ __align__(16) float sE[BDIM];
    __shared__ float red[128];
    const int t = blockIdx.x;
    const int m = threadIdx.x;

    for (int i = m; i < BDIM; i += 128) sE[i] = tags_embed[(size_t)t * BDIM + i];
    __syncthreads();

    float acc = tags_b[m];
    const float* Wr = tags_W + (size_t)m * BDIM;
    #pragma unroll 8
    for (int b = 0; b < BDIM; b += 4) {
        float4 w4 = *reinterpret_cast<const float4*>(Wr + b);
        float4 e4 = *reinterpret_cast<const float4*>(&sE[b]);
        acc += w4.x * e4.x + w4.y * e4.y + w4.z * e4.z + w4.w * e4.w;
    }
    Tbf[(size_t)t * MDIM + m] = (unsigned short)bf16_1(2.0f * acc);

    red[m] = acc * (2.0f * words_b[m] - acc);
    __syncthreads();
    for (int s = 64; s > 0; s >>= 1) {
        if (m < s) red[m] += red[m + s];
        __syncthreads();
    }
    if (m == 0) cvec[t] = red[0];
}

__global__ __launch_bounds__(256) void wt_kernel(
    const float* __restrict__ W, unsigned short* __restrict__ Wtbf)
{
    __shared__ float sT[32][33];
    const int bm = blockIdx.x & 3, bk = blockIdx.x >> 2;
    const int m0 = bm * 32, k0 = bk * 32;
    const int r = threadIdx.x >> 3, c = threadIdx.x & 7;

    f32x4 w4 = *reinterpret_cast<const f32x4*>(W + (size_t)(m0 + r) * BDIM + k0 + c * 4);
    sT[r][c * 4 + 0] = w4.x;  sT[r][c * 4 + 1] = w4.y;
    sT[r][c * 4 + 2] = w4.z;  sT[r][c * 4 + 3] = w4.w;
    __syncthreads();

    unsigned lo = bf16_2(sT[c * 4 + 0][r], sT[c * 4 + 1][r]);
    unsigned hi = bf16_2(sT[c * 4 + 2][r], sT[c * 4 + 3][r]);
    unsigned long long p = ((unsigned long long)hi << 32) | lo;
    *reinterpret_cast<unsigned long long*>(Wtbf + (size_t)(k0 + r) * MDIM + m0 + c * 4) = p;
}

// GtSl[s][tag][k%32], slice-major
__global__ __launch_bounds__(64) void gt_kernel(
    const unsigned short* __restrict__ Wtbf, const unsigned short* __restrict__ Tbf,
    unsigned short* __restrict__ GtSl)
{
    const int kt = blockIdx.x % 48, tg = blockIdx.x / 48;
    const int k0 = kt * 16, t0 = tg * 64;
    const int n = threadIdx.x & 15, q = threadIdx.x >> 4;

    bf16x8 a[4];
    #pragma unroll
    for (int ks = 0; ks < 4; ++ks)
        a[ks] = *reinterpret_cast<const bf16x8*>(
            Wtbf + (size_t)(k0 + n) * MDIM + ks * 32 + q * 8);

    const int s2  = kt >> 1;
    const int off = (kt & 1) * 16 + 4 * q;

    #pragma unroll
    for (int tt = 0; tt < 4; ++tt) {
        f32x4 acc = (f32x4){0.f, 0.f, 0.f, 0.f};
        #pragma unroll
        for (int ks = 0; ks < 4; ++ks) {
            bf16x8 b = *reinterpret_cast<const bf16x8*>(
                Tbf + (size_t)(t0 + tt * 16 + n) * MDIM + ks * 32 + q * 8);
            acc = __builtin_amdgcn_mfma_f32_16x16x32_bf16(a[ks], b, acc, 0, 0, 0);
        }
        unsigned lo = bf16_2(acc.x, acc.y);
        unsigned hi = bf16_2(acc.z, acc.w);
        unsigned long long p = ((unsigned long long)hi << 32) | lo;
        *reinterpret_cast<unsigned long long*>(
            GtSl + (size_t)s2 * SLB + (size_t)(t0 + tt * 16 + n) * KS + off) = p;
    }
}

// ---------------------------------------------------------------------------
// main: TRIPLE-BUFFERED sG, 2-slice DMA window. 4096 blocks x 1024 thr
// (16 waves, 1 block/CU). Wave v = tags v*32..+31 x 64 words; acc[2][4].
// Slice s: issue [E(s+2), D(s+2)x2 -> buf (s+2)%3]; ds_write E(s+1);
// compute from buf s%3; barrier vmcnt(3) retires D(s+1)x2 (issued LAST
// slice -> ~2 slice periods of latency tolerance).
// ---------------------------------------------------------------------------
__global__ __launch_bounds__(1024, 4) void main_kernel(
    const float* __restrict__ embed,                 // [N][768] fp32
    const unsigned short* __restrict__ GtSl,         // [24][512][32] bf16
    const float* __restrict__ cvec,                  // [512] fp32
    float* __restrict__ out_logp, float* __restrict__ out_p)
{
    __shared__ __align__(16) unsigned short sG[3 * SLB];      // 96 KB
    __shared__ __align__(16) unsigned short sE[2 * BW * KS];  // 8 KB
    __shared__ float sMx[16 * 64];
    __shared__ float sSm[16 * 64];

    const int tid  = threadIdx.x;
    const int lane = tid & 63;
    const int v    = tid >> 6;       // wave 0..15 -> tags v*32..+31
    const int n    = lane & 15;
    const int q    = lane >> 4;
    const int we   = tid >> 4;       // staging word 0..63
    const int kp   = tid & 15;       // staging 2-float granule
    const int w0   = blockIdx.x * BW;

    const float* eSrc = embed + (size_t)(w0 + we) * BDIM + kp * 2;

    // ---- prologue: D(0)->buf0, D(1)->buf1, E(0)->LDS; full drain once ----
    {
        f32x2 e0 = ntld2(eSrc);
        #pragma unroll
        for (int r = 0; r < 2; ++r)
            GLOAD16(sG + (r * 16 + v) * 512,
                    GtSl + (size_t)((r * 16 + v) * 64 + lane) * 8);
        #pragma unroll
        for (int r = 0; r < 2; ++r)
            GLOAD16(sG + SLB + (r * 16 + v) * 512,
                    GtSl + (size_t)SLB + (size_t)((r * 16 + v) * 64 + lane) * 8);
        *reinterpret_cast<unsigned*>(sE + we * KS + kp * 2) = bf16_2(e0.x, e0.y);
        asm volatile("s_waitcnt vmcnt(0) lgkmcnt(0)\n\ts_barrier" ::: "memory");
    }
    f32x2 eOld = ntld2(eSrc + KS);   // E(1), in flight

    f32x4 acc[2][4];
    #pragma unroll
    for (int mt = 0; mt < 2; ++mt)
        #pragma unroll
        for (int wt = 0; wt < 4; ++wt)
            acc[mt][wt] = (f32x4){0.f, 0.f, 0.f, 0.f};

    int esel = 0;   // sE read buffer parity for current slice

    // one slice: SV = slice idx (runtime), RB/DB = static sG buf indices
#define SLICE(SV, RB, DB, ISSUE, VMC)                                        \
    {                                                                        \
        f32x2 eN;                                                            \
        if (ISSUE) {                                                         \
            eN = ntld2(eSrc + ((SV) + 2) * KS);                              \
            _Pragma("unroll")                                                \
            for (int r = 0; r < 2; ++r)                                      \
                GLOAD16(sG + (DB) * SLB + (r * 16 + v) * 512,                \
                        GtSl + (size_t)((SV) + 2) * SLB                      \
                             + (size_t)((r * 16 + v) * 64 + lane) * 8);      \
        }                                                                    \
        if ((SV) + 1 < NSL)                                                  \
            *reinterpret_cast<unsigned*>(                                    \
                sE + (esel ^ 1) * (BW * KS) + we * KS + kp * 2) =            \
                bf16_2(eOld.x, eOld.y);                                      \
        {                                                                    \
            const unsigned short* sGc = sG + (RB) * SLB;                     \
            const unsigned short* sEc = sE + esel * (BW * KS);               \
            bf16x8 a0 = *reinterpret_cast<const bf16x8*>(                    \
                sGc + (v * 32 + n) * KS + q * 8);                            \
            bf16x8 a1 = *reinterpret_cast<const bf16x8*>(                    \
                sGc + (v * 32 + 16 + n) * KS + q * 8);                       \
            _Pragma("unroll")                                                \
            for (int wt = 0; wt < 4; ++wt) {                                 \
                bf16x8 b = *reinterpret_cast<const bf16x8*>(                 \
                    sEc + (wt * 16 + n) * KS + q * 8);                       \
                acc[0][wt] = __builtin_amdgcn_mfma_f32_16x16x32_bf16(        \
                    a0, b, acc[0][wt], 0, 0, 0);                             \
                acc[1][wt] = __builtin_amdgcn_mfma_f32_16x16x32_bf16(        \
                    a1, b, acc[1][wt], 0, 0, 0);                             \
            }                                                                \
        }                                                                    \
        if ((VMC) == 3)                                                      \
            asm volatile("s_waitcnt vmcnt(3) lgkmcnt(0)\n\ts_barrier" ::: "memory"); \
        else if ((VMC) == 0)                                                 \
            asm volatile("s_waitcnt vmcnt(0) lgkmcnt(0)\n\ts_barrier" ::: "memory"); \
        if (ISSUE) eOld = eN;                                                \
        esel ^= 1;                                                           \
    }

    // slices 0..20 (buffer pattern period 3, all full-issue)
    #pragma unroll 1
    for (int j = 0; j < 7; ++j) {
        const int s0 = 3 * j;
        SLICE(s0,     0, 2, 1, 3)
        SLICE(s0 + 1, 1, 0, 1, 3)
        SLICE(s0 + 2, 2, 1, 1, 3)
    }
    // tail: s=21 (issue E(23),D(23)->buf2), s=22 (drain), s=23 (compute only)
    SLICE(21, 0, 2, 1, 3)
    SLICE(22, 1, 2, 0, 0)
    SLICE(23, 2, 2, 0, -1)
#undef SLICE

    // ---- + cvec: tag = v*32 + mt*16 + 4q + r ----
    #pragma unroll
    for (int mt = 0; mt < 2; ++mt) {
        f32x4 c4 = *reinterpret_cast<const f32x4*>(cvec + v * 32 + mt * 16 + 4 * q);
        #pragma unroll
        for (int wt = 0; wt < 4; ++wt) acc[mt][wt] += c4;
    }

    // ---- per-word partial softmax (wave: 32 tags x 64 words) ----
    #pragma unroll
    for (int wt = 0; wt < 4; ++wt) {
        float m = -3.0e38f;
        #pragma unroll
        for (int mt = 0; mt < 2; ++mt)
            m = fmaxf(m, fmaxf(fmaxf(acc[mt][wt].x, acc[mt][wt].y),
                               fmaxf(acc[mt][wt].z, acc[mt][wt].w)));
        m = fmaxf(m, __shfl_xor(m, 16, 64));
        m = fmaxf(m, __shfl_xor(m, 32, 64));
        float ss = 0.f;
        #pragma unroll
        for (int mt = 0; mt < 2; ++mt)
            ss += __expf(acc[mt][wt].x - m) + __expf(acc[mt][wt].y - m)
                + __expf(acc[mt][wt].z - m) + __expf(acc[mt][wt].w - m);
        ss += __shfl_xor(ss, 16, 64);
        ss += __shfl_xor(ss, 32, 64);
        if (q == 0) {
            sMx[v * 64 + wt * 16 + n] = m;
            sSm[v * 64 + wt * 16 + n] = ss;
        }
    }
    __syncthreads();

    // ---- cross-wave combine + epilogue burst stores ----
    #pragma unroll
    for (int wt = 0; wt < 4; ++wt) {
        const int wd = wt * 16 + n;
        float M = sMx[wd];
        #pragma unroll
        for (int u = 1; u < 16; ++u) M = fmaxf(M, sMx[u * 64 + wd]);
        float S = 0.f;
        #pragma unroll
        for (int u = 0; u < 16; ++u)
            S += sSm[u * 64 + wd] * __expf(sMx[u * 64 + wd] - M);
        const float neg = M + __logf(S);

        const size_t rb = (size_t)(w0 + wd) * N_TAGS + v * 32 + 4 * q;
        #pragma unroll
        for (int mt = 0; mt < 2; ++mt) {
            f32x4 d = acc[mt][wt] - neg;
            *reinterpret_cast<f32x4*>(out_logp + rb + mt * 16) = d;
            f32x4 e;
            e.x = __expf(d.x); e.y = __expf(d.y);
            e.z = __expf(d.z); e.w = __expf(d.w);
            *reinterpret_cast<f32x4*>(out_p + rb + mt * 16) = e;
        }
    }
}

extern "C" void kernel_launch(void* const* d_in, const int* in_sizes, int n_in,
                              void* d_out, int out_size, void* d_ws, size_t ws_size,
                              hipStream_t stream) {
    const float* tags_embed  = (const float*)d_in[0];
    const float* words_embed = (const float*)d_in[1];
    const float* tags_W      = (const float*)d_in[2];
    const float* tags_b      = (const float*)d_in[3];
    const float* words_W     = (const float*)d_in[4];
    const float* words_b     = (const float*)d_in[5];

    float* out_logp = (float*)d_out;
    float* out_p    = out_logp + (size_t)N_WORDS * N_TAGS;

    // ws: Tbf [512][128] bf16 | cvec [512] f32 | Wtbf [768][128] bf16 |
    //     GtSl [24][512][32] bf16
    unsigned short* Tbf  = (unsigned short*)d_ws;
    float*          cvec = (float*)(Tbf + (size_t)N_TAGS * MDIM);
    unsigned short* Wtbf = (unsigned short*)(cvec + N_TAGS);
    unsigned short* GtSl = Wtbf + (size_t)BDIM * MDIM;

    tags_kernel<<<N_TAGS, 128, 0, stream>>>(tags_embed, tags_W, tags_b, words_b, Tbf, cvec);
    wt_kernel<<<96, 256, 0, stream>>>(words_W, Wtbf);
    gt_kernel<<<384, 64, 0, stream>>>(Wtbf, Tbf, GtSl);
    main_kernel<<<N_WORDS / BW, 1024, 0, stream>>>(
        words_embed, GtSl, cvec, out_logp, out_p);
}